// Round 13
// baseline (115.636 us; speedup 1.0000x reference)
//
#include <hip/hip_runtime.h>

#define AS_GLOBAL __attribute__((address_space(1)))
#define AS_LDS    __attribute__((address_space(3)))

typedef __bf16 bf16;
typedef __bf16 bf16x4 __attribute__((ext_vector_type(4)));
typedef __bf16 bf16x8 __attribute__((ext_vector_type(8)));
typedef float  f32x4  __attribute__((ext_vector_type(4)));
typedef unsigned short u16x8 __attribute__((ext_vector_type(8)));

__device__ __forceinline__ void gload16(const void* g, void* l) {
  __builtin_amdgcn_global_load_lds((const AS_GLOBAL unsigned int*)g,
                                   (AS_LDS unsigned int*)l, 16, 0, 0);
}

// swizzled LDS address for a [R][128B] row-major tile:
// stored_byte = row*128 + (bytecol ^ ((row&7)<<4))
__device__ __forceinline__ void* swz(void* base, int row, int bytecol) {
  return (char*)base + row * 128 + (bytecol ^ ((row & 7) << 4));
}

// compacted-column helpers: kept columns are s with !(s%3==1 && s>=4).
__device__ __forceinline__ int keptcnt(int X) { return X - ((X - 2) < 0 ? 0 : (X - 2) / 3); }
__device__ __forceinline__ int ci2s(int ci) {
  return 3 * ((ci - 2) >> 1) + 2 + ((ci - 2) & 1);
}
__device__ __forceinline__ int ci2s_full(int ci) {
  return ci < 2 ? ci : ci2s(ci);
}

// ---------------- fused prep: x->bf16 | 4x W^T | bias concat --------------
__global__ __launch_bounds__(256) void k_prep(const float* __restrict__ x,
                                              const float* __restrict__ Wq,
                                              const float* __restrict__ Wk,
                                              const float* __restrict__ Wv,
                                              const float* __restrict__ Wp,
                                              const float* __restrict__ bq,
                                              const float* __restrict__ bk,
                                              const float* __restrict__ bv,
                                              bf16* __restrict__ xb,
                                              bf16* __restrict__ wqkvT,
                                              bf16* __restrict__ wpT,
                                              float* __restrict__ bc) {
  int blk = blockIdx.x;
  if (blk < 2048) {
    int i = blk * 256 + threadIdx.x;
    const float4* p = (const float4*)(x + (size_t)i * 8);
    float4 a = p[0], b = p[1];
    bf16x8 v;
    v[0] = (bf16)a.x; v[1] = (bf16)a.y; v[2] = (bf16)a.z; v[3] = (bf16)a.w;
    v[4] = (bf16)b.x; v[5] = (bf16)b.y; v[6] = (bf16)b.z; v[7] = (bf16)b.w;
    *(bf16x8*)(xb + (size_t)i * 8) = v;
  } else if (blk < 4096) {
    int wblk = blk - 2048;
    int sel = wblk >> 9;
    const float* W = (sel == 0) ? Wq : (sel == 1) ? Wk : (sel == 2) ? Wv : Wp;
    bf16* dst = (sel < 3) ? (wqkvT + (size_t)sel * 1024 * 1024) : wpT;
    int lin = (wblk & 511) * 256 + threadIdx.x;
    int n = lin & 1023, kc = lin >> 10;
    bf16x8 v;
#pragma unroll
    for (int j = 0; j < 8; ++j) v[j] = (bf16)W[(size_t)(kc * 8 + j) * 1024 + n];
    *(bf16x8*)&dst[(size_t)n * 1024 + kc * 8] = v;
  } else {
    int i = (blk - 4096) * 256 + threadIdx.x;   // 0..3071
    bc[i] = (i < 1024) ? bq[i] : (i < 2048 ? bk[i - 1024] : bv[i - 2048]);
  }
}

// ---------------- V compact: gather + transpose -> Vc[bh][64][1408] -------
__global__ __launch_bounds__(256) void k_compact(const bf16* __restrict__ qkv,
                                                 bf16* __restrict__ vc) {
  __shared__ unsigned L[32 * 65];
  int blk = blockIdx.x;                 // 32 bh * 22 cichunks = 704
  int tid = threadIdx.x;
  int bh = blk / 22, cc = blk % 22;
  int b = bh >> 4, h = bh & 15;
  int ci0 = cc * 64;
  int p = tid >> 3, d0 = (tid & 7) * 8;
  int s0 = ci2s_full(ci0 + 2 * p), s1 = ci2s_full(ci0 + 2 * p + 1);
  u16x8 e = {}, od = {};
  if (s0 < 2048)
    e = *(const u16x8*)&qkv[(size_t)(b * 2048 + s0) * 3072 + 2048 + h * 64 + d0];
  if (s1 < 2048)
    od = *(const u16x8*)&qkv[(size_t)(b * 2048 + s1) * 3072 + 2048 + h * 64 + d0];
#pragma unroll
  for (int k2 = 0; k2 < 8; ++k2)
    L[p * 65 + d0 + k2] = (unsigned)e[k2] | ((unsigned)od[k2] << 16);
  __syncthreads();
#pragma unroll
  for (int it = 0; it < 2; ++it) {
    int d = it * 32 + (tid >> 3), jg = tid & 7;
    unsigned q4[4];
#pragma unroll
    for (int jj = 0; jj < 4; ++jj) q4[jj] = L[(jg * 4 + jj) * 65 + d];
    *(uint4*)&vc[((size_t)bh * 64 + d) * 1408 + ci0 + jg * 8] = *(uint4*)q4;
  }
}

// ---------------- 128^2 dbuf GEMM: C[M,N] = A[M,K] @ Bt[N,K]^T + bias ------
template <typename OutT>
__global__ __launch_bounds__(256) void k_gemm_bt(const bf16* __restrict__ A,
                                                 const bf16* __restrict__ Bt,
                                                 const float* __restrict__ bias,
                                                 OutT* __restrict__ C,
                                                 int K, int N) {
  __shared__ bf16 As[2][128 * 32];
  __shared__ bf16 Bs[2][128 * 32];
  const int tid = threadIdx.x;
  const int w = tid >> 6, l = tid & 63, g = l >> 4, c = l & 15;
  const int wr = w >> 1, wc = w & 1;
  int lin = blockIdx.y * gridDim.x + blockIdx.x;
  int chunk = (gridDim.x * gridDim.y) >> 3;
  int nl = (lin & 7) * chunk + (lin >> 3);
  const int row0 = (nl % gridDim.x) * 128, col0 = (nl / gridDim.x) * 128;
  f32x4 acc[4][4] = {};

  auto stage = [&](int buf, int k0) {
#pragma unroll
    for (int it = 0; it < 2; ++it) {
      int idx = it * 256 + tid;
      int r = idx >> 2, cc = idx & 3;
      int jj = cc ^ ((r >> 1) & 3);
      gload16(A  + (size_t)(row0 + r) * K + k0 + jj * 8, &As[buf][idx * 8]);
      gload16(Bt + (size_t)(col0 + r) * K + k0 + jj * 8, &Bs[buf][idx * 8]);
    }
  };

  stage(0, 0);
  int cur = 0;
#pragma unroll 1
  for (int k0 = 0; k0 < K; k0 += 32) {
    __syncthreads();   // drains vmcnt (stage(k0) landed) + full memory fence

    if (k0 + 32 < K) stage(cur ^ 1, k0 + 32);

    bf16x8 af[4], bfr[4];
#pragma unroll
    for (int m = 0; m < 4; ++m) {
      int row = wr * 64 + m * 16 + c;
      af[m] = *(const bf16x8*)&As[cur][row * 32 + (g ^ ((row >> 1) & 3)) * 8];
    }
#pragma unroll
    for (int n = 0; n < 4; ++n) {
      int row = wc * 64 + n * 16 + c;
      bfr[n] = *(const bf16x8*)&Bs[cur][row * 32 + (g ^ ((row >> 1) & 3)) * 8];
    }
#pragma unroll
    for (int m = 0; m < 4; ++m)
#pragma unroll
      for (int n = 0; n < 4; ++n)
        acc[m][n] = __builtin_amdgcn_mfma_f32_16x16x32_bf16(af[m], bfr[n],
                                                            acc[m][n], 0, 0, 0);
    cur ^= 1;
  }

#pragma unroll
  for (int m = 0; m < 4; ++m) {
    int row = row0 + wr * 64 + m * 16 + g * 4;
#pragma unroll
    for (int n = 0; n < 4; ++n) {
      int col = col0 + wc * 64 + n * 16 + c;
      float bv = bias[col];
#pragma unroll
      for (int r = 0; r < 4; ++r) {
        float v = acc[m][n][r] + bv;
        C[(size_t)(row + r) * N + col] = (OutT)v;
      }
    }
  }
}

// ---------------- flash attention v9: 128-q-tile, K direct from qkv -------
// 512 blocks; per block 128 q-rows; 4 waves each own TWO 16-row q-subtiles
// (A at +w*16, B at +64+w*16). K/V LDS tiles + ds_reads shared across both
// subtiles (K frag read once -> 4 MFMAs). K staged straight from qkv with
// per-lane gather source (dest linear, source per-lane: legal for
// global_load_lds). Pad rows (s>=2048) clamp the LOAD address only; the
// mask uses the real s, and pads occur only in t=21 which is >= every
// wave's boundary tile, so they are always causally masked.
// Balance: slot mapping qt2 in {r8, 15-r8}; XCD: idx%8 == bh%8.
__global__ __launch_bounds__(256, 2) void k_attn(const bf16* __restrict__ qkv,
                                                 const bf16* __restrict__ vc,
                                                 bf16* __restrict__ att) {
  const int idx = blockIdx.x;               // 512
  const int slot = idx >> 8, j = idx & 255;
  const int r8 = j >> 5, bh = j & 31;
  const int b = bh >> 4, h = bh & 15;
  const int qt2 = (slot == 0) ? r8 : 15 - r8;

  const int tid = threadIdx.x;
  const int w = tid >> 6, l = tid & 63, g = l >> 4, c = l & 15;
  const int qA = qt2 * 128 + w * 16, qB = qA + 64;
  const int qqA = qA + c, qqB = qB + c;

  const int nt = (keptcnt(qt2 * 128 + 128) + 63) >> 6;
  const int tmA = keptcnt(qA + 1) >> 6;
  const int tmB = keptcnt(qB + 1) >> 6;

  __shared__ bf16 Ks[2][64 * 64];       // [ci][d] swizzled (8KB each)
  __shared__ bf16 Vs[2][64 * 64];       // [d][ci] swizzled
  __shared__ bf16 Plds[4][2][16 * 64];  // per wave x subtile (2KB each)

  const bf16* vgc = vc + (size_t)bh * 64 * 1408;

  auto stage = [&](int buf, int t) {
    int s0 = t * 64;
#pragma unroll
    for (int it = 0; it < 2; ++it) {
      int ch = it * 256 + tid;
      int rr = ch >> 3, jj = (ch & 7) ^ (rr & 7);
      int s = ci2s_full(s0 + rr);
      s = (s < 2048) ? s : 0;             // pad: load row 0; masked by s<=qq
      gload16(qkv + (size_t)(b * 2048 + s) * 3072 + 1024 + h * 64 + jj * 8,
              &Ks[buf][ch * 8]);
      gload16(vgc + (size_t)rr * 1408 + s0 + jj * 8, &Vs[buf][ch * 8]);
    }
  };

  // Q B-frags for both subtiles, pre-scaled by 0.125 (exact in bf16)
  const bf16* qbA = qkv + (size_t)(b * 2048 + qqA) * 3072 + h * 64 + g * 8;
  const bf16* qbB = qkv + (size_t)(b * 2048 + qqB) * 3072 + h * 64 + g * 8;
  bf16x8 qf0A = *(const bf16x8*)qbA, qf1A = *(const bf16x8*)(qbA + 32);
  bf16x8 qf0B = *(const bf16x8*)qbB, qf1B = *(const bf16x8*)(qbB + 32);
#pragma unroll
  for (int jq = 0; jq < 8; ++jq) {
    qf0A[jq] = (bf16)((float)qf0A[jq] * 0.125f);
    qf1A[jq] = (bf16)((float)qf1A[jq] * 0.125f);
    qf0B[jq] = (bf16)((float)qf0B[jq] * 0.125f);
    qf1B[jq] = (bf16)((float)qf1B[jq] * 0.125f);
  }

  f32x4 oA[4] = {}, oB[4] = {};
  float mA = -1e30f, lA = 0.f, mB = -1e30f, lB = 0.f;

  stage(0, 0);

  int cur = 0;
#pragma unroll 1
  for (int t = 0; t < nt; ++t) {
    __syncthreads();   // stage(t) landed everywhere; all waves done with t-1

    if (t + 1 < nt) stage(cur ^ 1, t + 1);

    // ---- S^T = K Q^T : K frags read ONCE, feed both subtiles ----
    f32x4 sA[4] = {}, sB[4] = {};
#pragma unroll
    for (int st = 0; st < 4; ++st) {
      bf16x8 ka  = *(const bf16x8*)swz(&Ks[cur][0], st * 16 + c, g * 16);
      bf16x8 kb2 = *(const bf16x8*)swz(&Ks[cur][0], st * 16 + c, 64 + g * 16);
      sA[st] = __builtin_amdgcn_mfma_f32_16x16x32_bf16(ka,  qf0A, sA[st], 0, 0, 0);
      sA[st] = __builtin_amdgcn_mfma_f32_16x16x32_bf16(kb2, qf1A, sA[st], 0, 0, 0);
      sB[st] = __builtin_amdgcn_mfma_f32_16x16x32_bf16(ka,  qf0B, sB[st], 0, 0, 0);
      sB[st] = __builtin_amdgcn_mfma_f32_16x16x32_bf16(kb2, qf1B, sB[st], 0, 0, 0);
    }

    // ---- subtile A: mask + lane-local online softmax ----
    {
      float mloc = -1e30f;
      if (t >= tmA) {
#pragma unroll
        for (int st = 0; st < 4; ++st)
#pragma unroll
          for (int r = 0; r < 4; ++r) {
            int ci = t * 64 + st * 16 + g * 4 + r;
            int s = ci2s(ci);
            if (t == 0) s = (ci < 2) ? ci : s;
            float v = (s <= qqA) ? sA[st][r] : -1e30f;
            sA[st][r] = v;
            mloc = fmaxf(mloc, v);
          }
      } else {
#pragma unroll
        for (int st = 0; st < 4; ++st)
#pragma unroll
          for (int r = 0; r < 4; ++r) mloc = fmaxf(mloc, sA[st][r]);
      }
      mloc = fmaxf(mloc, __shfl_xor(mloc, 16));
      mloc = fmaxf(mloc, __shfl_xor(mloc, 32));
      float mn = fmaxf(mA, mloc);
      float al = __expf(mA - mn);
      mA = mn;
      float rs = 0.f;
#pragma unroll
      for (int st = 0; st < 4; ++st) {
        float p0 = __expf(sA[st][0] - mn);
        float p1 = __expf(sA[st][1] - mn);
        float p2 = __expf(sA[st][2] - mn);
        float p3 = __expf(sA[st][3] - mn);
        rs += (p0 + p1) + (p2 + p3);
        bf16x4 pk = {(bf16)p0, (bf16)p1, (bf16)p2, (bf16)p3};
        *(bf16x4*)swz(&Plds[w][0][0], c, st * 32 + g * 8) = pk;
      }
      rs += __shfl_xor(rs, 16);
      rs += __shfl_xor(rs, 32);
      lA = lA * al + rs;
#pragma unroll
      for (int dc = 0; dc < 4; ++dc)
#pragma unroll
        for (int r = 0; r < 4; ++r) oA[dc][r] *= al;
    }
    // ---- subtile B ----
    {
      float mloc = -1e30f;
      if (t >= tmB) {
#pragma unroll
        for (int st = 0; st < 4; ++st)
#pragma unroll
          for (int r = 0; r < 4; ++r) {
            int ci = t * 64 + st * 16 + g * 4 + r;
            int s = ci2s(ci);
            if (t == 0) s = (ci < 2) ? ci : s;
            float v = (s <= qqB) ? sB[st][r] : -1e30f;
            sB[st][r] = v;
            mloc = fmaxf(mloc, v);
          }
      } else {
#pragma unroll
        for (int st = 0; st < 4; ++st)
#pragma unroll
          for (int r = 0; r < 4; ++r) mloc = fmaxf(mloc, sB[st][r]);
      }
      mloc = fmaxf(mloc, __shfl_xor(mloc, 16));
      mloc = fmaxf(mloc, __shfl_xor(mloc, 32));
      float mn = fmaxf(mB, mloc);
      float al = __expf(mB - mn);
      mB = mn;
      float rs = 0.f;
#pragma unroll
      for (int st = 0; st < 4; ++st) {
        float p0 = __expf(sB[st][0] - mn);
        float p1 = __expf(sB[st][1] - mn);
        float p2 = __expf(sB[st][2] - mn);
        float p3 = __expf(sB[st][3] - mn);
        rs += (p0 + p1) + (p2 + p3);
        bf16x4 pk = {(bf16)p0, (bf16)p1, (bf16)p2, (bf16)p3};
        *(bf16x4*)swz(&Plds[w][1][0], c, st * 32 + g * 8) = pk;
      }
      rs += __shfl_xor(rs, 16);
      rs += __shfl_xor(rs, 32);
      lB = lB * al + rs;
#pragma unroll
      for (int dc = 0; dc < 4; ++dc)
#pragma unroll
        for (int r = 0; r < 4; ++r) oB[dc][r] *= al;
    }

    // wave-private P cross-lane round trip (rule #18 fence pair)
    asm volatile("s_waitcnt lgkmcnt(0)" ::: "memory");
    __builtin_amdgcn_sched_barrier(0);

    // ---- O^T += V^T P : V frags read ONCE, feed both subtiles ----
#pragma unroll
    for (int kk = 0; kk < 2; ++kk) {
      bf16x8 pfA = *(const bf16x8*)swz(&Plds[w][0][0], c, kk * 64 + g * 16);
      bf16x8 pfB = *(const bf16x8*)swz(&Plds[w][1][0], c, kk * 64 + g * 16);
#pragma unroll
      for (int dc = 0; dc < 4; ++dc) {
        bf16x8 vf = *(const bf16x8*)swz(&Vs[cur][0], dc * 16 + c, kk * 64 + g * 16);
        oA[dc] = __builtin_amdgcn_mfma_f32_16x16x32_bf16(vf, pfA, oA[dc], 0, 0, 0);
        oB[dc] = __builtin_amdgcn_mfma_f32_16x16x32_bf16(vf, pfB, oB[dc], 0, 0, 0);
      }
    }

    cur ^= 1;
  }

  // ---- epilogue: O^T -> LDS transpose -> coalesced b128 stores ----
  float invA = 1.f / lA, invB = 1.f / lB;
#pragma unroll
  for (int dc = 0; dc < 4; ++dc) {
    bf16x4 a4 = {(bf16)(oA[dc][0] * invA), (bf16)(oA[dc][1] * invA),
                 (bf16)(oA[dc][2] * invA), (bf16)(oA[dc][3] * invA)};
    bf16x4 b4 = {(bf16)(oB[dc][0] * invB), (bf16)(oB[dc][1] * invB),
                 (bf16)(oB[dc][2] * invB), (bf16)(oB[dc][3] * invB)};
    *(bf16x4*)swz(&Plds[w][0][0], c, dc * 32 + g * 8) = a4;
    *(bf16x4*)swz(&Plds[w][1][0], c, dc * 32 + g * 8) = b4;
  }
  asm volatile("s_waitcnt lgkmcnt(0)" ::: "memory");
  __builtin_amdgcn_sched_barrier(0);
#pragma unroll
  for (int p = 0; p < 2; ++p) {
    int row = p * 8 + (l >> 3);
    bf16x8 va = *(const bf16x8*)swz(&Plds[w][0][0], row, (l & 7) * 16);
    bf16x8 vb = *(const bf16x8*)swz(&Plds[w][1][0], row, (l & 7) * 16);
    *(bf16x8*)&att[(size_t)(b * 2048 + qA + row) * 1024 + h * 64 + (l & 7) * 8] = va;
    *(bf16x8*)&att[(size_t)(b * 2048 + qB + row) * 1024 + h * 64 + (l & 7) * 8] = vb;
  }
}

// ---------------- launcher ----------------
extern "C" void kernel_launch(void* const* d_in, const int* in_sizes, int n_in,
                              void* d_out, int out_size, void* d_ws, size_t ws_size,
                              hipStream_t stream) {
  const float* x  = (const float*)d_in[0];
  const float* Wq = (const float*)d_in[1];
  const float* bq = (const float*)d_in[2];
  const float* Wk = (const float*)d_in[3];
  const float* bk = (const float*)d_in[4];
  const float* Wv = (const float*)d_in[5];
  const float* bv = (const float*)d_in[6];
  const float* Wp = (const float*)d_in[7];
  const float* bp = (const float*)d_in[8];
  float* out = (float*)d_out;

  char* ws = (char*)d_ws;
  const size_t MB = 1024 * 1024;
  bf16*  xb    = (bf16*)(ws);             // 8 MB [4096][1024]; reused as att
  bf16*  wqkvT = (bf16*)(ws + 8 * MB);    // 6 MB [3072][1024]
  bf16*  wpT   = (bf16*)(ws + 14 * MB);   // 2 MB [1024][1024]
  float* bcat  = (float*)(ws + 16 * MB);  // 12 KB
  bf16*  qkv   = (bf16*)(ws + 17 * MB);   // 24 MB [4096][3072]
  bf16*  vcb   = (bf16*)(ws + 41 * MB);   // 5.5 MB [32][64][1408]
  bf16*  att   = xb;                      // alias: xb dead after QKV GEMM

  // 1: all preps (cvt + 4x W^T + bias concat)
  k_prep<<<4108, 256, 0, stream>>>(x, Wq, Wk, Wv, Wp, bq, bk, bv,
                                   xb, wqkvT, wpT, bcat);
  // 2: QKV GEMM [4096,1024]x[1024,3072]
  k_gemm_bt<bf16><<<dim3(32, 24), 256, 0, stream>>>(xb, wqkvT, bcat, qkv, 1024, 3072);
  // 3: V gather/transpose only (K read directly from qkv by attn)
  k_compact<<<704, 256, 0, stream>>>(qkv, vcb);
  // 4: attention (512 blocks, 128 q-rows each)
  k_attn<<<512, 256, 0, stream>>>(qkv, vcb, att);
  // 5: output projection
  k_gemm_bt<float><<<dim3(32, 8), 256, 0, stream>>>(att, wpT, bp, out, 1024, 1024);
}

// Round 14
// 106.055 us; speedup vs baseline: 1.0903x; 1.0903x over previous
//
#include <hip/hip_runtime.h>

#define AS_GLOBAL __attribute__((address_space(1)))
#define AS_LDS    __attribute__((address_space(3)))

typedef __bf16 bf16;
typedef __bf16 bf16x4 __attribute__((ext_vector_type(4)));
typedef __bf16 bf16x8 __attribute__((ext_vector_type(8)));
typedef float  f32x4  __attribute__((ext_vector_type(4)));
typedef unsigned short u16x8 __attribute__((ext_vector_type(8)));

__device__ __forceinline__ void gload16(const void* g, void* l) {
  __builtin_amdgcn_global_load_lds((const AS_GLOBAL unsigned int*)g,
                                   (AS_LDS unsigned int*)l, 16, 0, 0);
}

// swizzled LDS address for a [R][128B] row-major tile:
// stored_byte = row*128 + (bytecol ^ ((row&7)<<4))
__device__ __forceinline__ void* swz(void* base, int row, int bytecol) {
  return (char*)base + row * 128 + (bytecol ^ ((row & 7) << 4));
}

// compacted-column helpers: kept columns are s with !(s%3==1 && s>=4).
__device__ __forceinline__ int keptcnt(int X) { return X - ((X - 2) < 0 ? 0 : (X - 2) / 3); }
__device__ __forceinline__ int ci2s(int ci) {
  return 3 * ((ci - 2) >> 1) + 2 + ((ci - 2) & 1);
}
__device__ __forceinline__ int ci2s_full(int ci) {
  return ci < 2 ? ci : ci2s(ci);
}

// ---------------- fused prep: x->bf16 | 4x W^T | bias concat --------------
__global__ __launch_bounds__(256) void k_prep(const float* __restrict__ x,
                                              const float* __restrict__ Wq,
                                              const float* __restrict__ Wk,
                                              const float* __restrict__ Wv,
                                              const float* __restrict__ Wp,
                                              const float* __restrict__ bq,
                                              const float* __restrict__ bk,
                                              const float* __restrict__ bv,
                                              bf16* __restrict__ xb,
                                              bf16* __restrict__ wqkvT,
                                              bf16* __restrict__ wpT,
                                              float* __restrict__ bc) {
  int blk = blockIdx.x;
  if (blk < 2048) {
    int i = blk * 256 + threadIdx.x;
    const float4* p = (const float4*)(x + (size_t)i * 8);
    float4 a = p[0], b = p[1];
    bf16x8 v;
    v[0] = (bf16)a.x; v[1] = (bf16)a.y; v[2] = (bf16)a.z; v[3] = (bf16)a.w;
    v[4] = (bf16)b.x; v[5] = (bf16)b.y; v[6] = (bf16)b.z; v[7] = (bf16)b.w;
    *(bf16x8*)(xb + (size_t)i * 8) = v;
  } else if (blk < 4096) {
    int wblk = blk - 2048;
    int sel = wblk >> 9;
    const float* W = (sel == 0) ? Wq : (sel == 1) ? Wk : (sel == 2) ? Wv : Wp;
    bf16* dst = (sel < 3) ? (wqkvT + (size_t)sel * 1024 * 1024) : wpT;
    int lin = (wblk & 511) * 256 + threadIdx.x;
    int n = lin & 1023, kc = lin >> 10;
    bf16x8 v;
#pragma unroll
    for (int j = 0; j < 8; ++j) v[j] = (bf16)W[(size_t)(kc * 8 + j) * 1024 + n];
    *(bf16x8*)&dst[(size_t)n * 1024 + kc * 8] = v;
  } else {
    int i = (blk - 4096) * 256 + threadIdx.x;   // 0..3071
    bc[i] = (i < 1024) ? bq[i] : (i < 2048 ? bk[i - 1024] : bv[i - 2048]);
  }
}

// ---------------- V compact: gather + transpose -> Vc[bh][64][1408] -------
__global__ __launch_bounds__(256) void k_compact(const bf16* __restrict__ qkv,
                                                 bf16* __restrict__ vc) {
  __shared__ unsigned L[32 * 65];
  int blk = blockIdx.x;                 // 32 bh * 22 cichunks = 704
  int tid = threadIdx.x;
  int bh = blk / 22, cc = blk % 22;
  int b = bh >> 4, h = bh & 15;
  int ci0 = cc * 64;
  int p = tid >> 3, d0 = (tid & 7) * 8;
  int s0 = ci2s_full(ci0 + 2 * p), s1 = ci2s_full(ci0 + 2 * p + 1);
  u16x8 e = {}, od = {};
  if (s0 < 2048)
    e = *(const u16x8*)&qkv[(size_t)(b * 2048 + s0) * 3072 + 2048 + h * 64 + d0];
  if (s1 < 2048)
    od = *(const u16x8*)&qkv[(size_t)(b * 2048 + s1) * 3072 + 2048 + h * 64 + d0];
#pragma unroll
  for (int k2 = 0; k2 < 8; ++k2)
    L[p * 65 + d0 + k2] = (unsigned)e[k2] | ((unsigned)od[k2] << 16);
  __syncthreads();
#pragma unroll
  for (int it = 0; it < 2; ++it) {
    int d = it * 32 + (tid >> 3), jg = tid & 7;
    unsigned q4[4];
#pragma unroll
    for (int jj = 0; jj < 4; ++jj) q4[jj] = L[(jg * 4 + jj) * 65 + d];
    *(uint4*)&vc[((size_t)bh * 64 + d) * 1408 + ci0 + jg * 8] = *(uint4*)q4;
  }
}

// ---------------- 128^2 dbuf GEMM: C[M,N] = A[M,K] @ Bt[N,K]^T + bias ------
template <typename OutT>
__global__ __launch_bounds__(256) void k_gemm_bt(const bf16* __restrict__ A,
                                                 const bf16* __restrict__ Bt,
                                                 const float* __restrict__ bias,
                                                 OutT* __restrict__ C,
                                                 int K, int N) {
  __shared__ bf16 As[2][128 * 32];
  __shared__ bf16 Bs[2][128 * 32];
  const int tid = threadIdx.x;
  const int w = tid >> 6, l = tid & 63, g = l >> 4, c = l & 15;
  const int wr = w >> 1, wc = w & 1;
  int lin = blockIdx.y * gridDim.x + blockIdx.x;
  int chunk = (gridDim.x * gridDim.y) >> 3;
  int nl = (lin & 7) * chunk + (lin >> 3);
  const int row0 = (nl % gridDim.x) * 128, col0 = (nl / gridDim.x) * 128;
  f32x4 acc[4][4] = {};

  auto stage = [&](int buf, int k0) {
#pragma unroll
    for (int it = 0; it < 2; ++it) {
      int idx = it * 256 + tid;
      int r = idx >> 2, cc = idx & 3;
      int jj = cc ^ ((r >> 1) & 3);
      gload16(A  + (size_t)(row0 + r) * K + k0 + jj * 8, &As[buf][idx * 8]);
      gload16(Bt + (size_t)(col0 + r) * K + k0 + jj * 8, &Bs[buf][idx * 8]);
    }
  };

  stage(0, 0);
  int cur = 0;
#pragma unroll 1
  for (int k0 = 0; k0 < K; k0 += 32) {
    __syncthreads();   // drains vmcnt (stage(k0) landed) + full memory fence

    if (k0 + 32 < K) stage(cur ^ 1, k0 + 32);

    bf16x8 af[4], bfr[4];
#pragma unroll
    for (int m = 0; m < 4; ++m) {
      int row = wr * 64 + m * 16 + c;
      af[m] = *(const bf16x8*)&As[cur][row * 32 + (g ^ ((row >> 1) & 3)) * 8];
    }
#pragma unroll
    for (int n = 0; n < 4; ++n) {
      int row = wc * 64 + n * 16 + c;
      bfr[n] = *(const bf16x8*)&Bs[cur][row * 32 + (g ^ ((row >> 1) & 3)) * 8];
    }
#pragma unroll
    for (int m = 0; m < 4; ++m)
#pragma unroll
      for (int n = 0; n < 4; ++n)
        acc[m][n] = __builtin_amdgcn_mfma_f32_16x16x32_bf16(af[m], bfr[n],
                                                            acc[m][n], 0, 0, 0);
    cur ^= 1;
  }

#pragma unroll
  for (int m = 0; m < 4; ++m) {
    int row = row0 + wr * 64 + m * 16 + g * 4;
#pragma unroll
    for (int n = 0; n < 4; ++n) {
      int col = col0 + wc * 64 + n * 16 + c;
      float bv = bias[col];
#pragma unroll
      for (int r = 0; r < 4; ++r) {
        float v = acc[m][n][r] + bv;
        C[(size_t)(row + r) * N + col] = (OutT)v;
      }
    }
  }
}

// ---------------- flash attention v10: R12 geometry + K direct from qkv ---
// 1024 blocks, 64 q-rows, 4 waves, 40KB LDS, 4 blocks/CU (R12-proven).
// K staged straight from qkv (per-lane gather source, linear LDS dest);
// pad rows (s>=2048) clamp the LOAD address only — the mask uses the real
// s so they are always causally masked (max qq = 2047).
__global__ __launch_bounds__(256, 4) void k_attn(const bf16* __restrict__ qkv,
                                                 const bf16* __restrict__ vc,
                                                 bf16* __restrict__ att) {
  const int idx = blockIdx.x;
  const int slot = idx >> 8, j = idx & 255;
  const int r8 = j >> 5, bh = j & 31;
  const int b = bh >> 4, h = bh & 15;
  int qt;
  switch (slot) {
    case 0: qt = r8;       break;
    case 1: qt = 31 - r8;  break;
    case 2: qt = r8 + 8;   break;
    default: qt = 23 - r8; break;
  }

  const int tid = threadIdx.x;
  const int w = tid >> 6, l = tid & 63, g = l >> 4, c = l & 15;
  const int qw0 = qt * 64 + w * 16;
  const int qq = qw0 + c;

  const int nt = (keptcnt(qt * 64 + 64) + 63) >> 6;
  const int tmaskw = keptcnt(qw0 + 1) >> 6;

  __shared__ bf16 Ks[2][64 * 64];
  __shared__ bf16 Vs[2][64 * 64];
  __shared__ bf16 Plds[4][16 * 64];

  const bf16* vgc = vc + (size_t)bh * 64 * 1408;

  auto stage = [&](int buf, int t) {
    int s0 = t * 64;
#pragma unroll
    for (int it = 0; it < 2; ++it) {
      int ch = it * 256 + tid;
      int rr = ch >> 3, jj = (ch & 7) ^ (rr & 7);
      int s = ci2s_full(s0 + rr);
      s = (s < 2048) ? s : 0;             // pad: load row 0; masked by s<=qq
      gload16(qkv + (size_t)(b * 2048 + s) * 3072 + 1024 + h * 64 + jj * 8,
              &Ks[buf][ch * 8]);
      gload16(vgc + (size_t)rr * 1408 + s0 + jj * 8, &Vs[buf][ch * 8]);
    }
  };

  const bf16* qb = qkv + (size_t)(b * 2048 + qq) * 3072 + h * 64 + g * 8;
  bf16x8 qf0 = *(const bf16x8*)qb;
  bf16x8 qf1 = *(const bf16x8*)(qb + 32);
#pragma unroll
  for (int jq = 0; jq < 8; ++jq) {
    qf0[jq] = (bf16)((float)qf0[jq] * 0.125f);
    qf1[jq] = (bf16)((float)qf1[jq] * 0.125f);
  }

  f32x4 o[4] = {};
  float mrow = -1e30f, ell = 0.f;

  stage(0, 0);

  int cur = 0;
#pragma unroll 1
  for (int t = 0; t < nt; ++t) {
    __syncthreads();   // stage(t) landed everywhere; all waves done with t-1

    if (t + 1 < nt) stage(cur ^ 1, t + 1);

    f32x4 ss[4] = {};
#pragma unroll
    for (int st = 0; st < 4; ++st) {
      bf16x8 ka  = *(const bf16x8*)swz(&Ks[cur][0], st * 16 + c, g * 16);
      bf16x8 kb2 = *(const bf16x8*)swz(&Ks[cur][0], st * 16 + c, 64 + g * 16);
      ss[st] = __builtin_amdgcn_mfma_f32_16x16x32_bf16(ka,  qf0, ss[st], 0, 0, 0);
      ss[st] = __builtin_amdgcn_mfma_f32_16x16x32_bf16(kb2, qf1, ss[st], 0, 0, 0);
    }

    float mloc = -1e30f;
    if (t >= tmaskw) {
#pragma unroll
      for (int st = 0; st < 4; ++st)
#pragma unroll
        for (int r = 0; r < 4; ++r) {
          int ci = t * 64 + st * 16 + g * 4 + r;
          int s = ci2s(ci);
          if (t == 0) s = (ci < 2) ? ci : s;
          float v = (s <= qq) ? ss[st][r] : -1e30f;
          ss[st][r] = v;
          mloc = fmaxf(mloc, v);
        }
    } else {
#pragma unroll
      for (int st = 0; st < 4; ++st)
#pragma unroll
        for (int r = 0; r < 4; ++r) mloc = fmaxf(mloc, ss[st][r]);
    }
    mloc = fmaxf(mloc, __shfl_xor(mloc, 16));
    mloc = fmaxf(mloc, __shfl_xor(mloc, 32));

    float mn = fmaxf(mrow, mloc);
    float al = __expf(mrow - mn);
    mrow = mn;
    float rsum = 0.f;
#pragma unroll
    for (int st = 0; st < 4; ++st) {
      float p0 = __expf(ss[st][0] - mn);
      float p1 = __expf(ss[st][1] - mn);
      float p2 = __expf(ss[st][2] - mn);
      float p3 = __expf(ss[st][3] - mn);
      rsum += (p0 + p1) + (p2 + p3);
      bf16x4 pk = {(bf16)p0, (bf16)p1, (bf16)p2, (bf16)p3};
      *(bf16x4*)swz(&Plds[w][0], c, st * 32 + g * 8) = pk;
    }
    rsum += __shfl_xor(rsum, 16);
    rsum += __shfl_xor(rsum, 32);
    ell = ell * al + rsum;
#pragma unroll
    for (int dc = 0; dc < 4; ++dc)
#pragma unroll
      for (int r = 0; r < 4; ++r) o[dc][r] *= al;

    // wave-private P cross-lane round trip (rule #18 fence pair)
    asm volatile("s_waitcnt lgkmcnt(0)" ::: "memory");
    __builtin_amdgcn_sched_barrier(0);

#pragma unroll
    for (int kk = 0; kk < 2; ++kk) {
      bf16x8 pf = *(const bf16x8*)swz(&Plds[w][0], c, kk * 64 + g * 16);
#pragma unroll
      for (int dc = 0; dc < 4; ++dc) {
        bf16x8 vf = *(const bf16x8*)swz(&Vs[cur][0], dc * 16 + c, kk * 64 + g * 16);
        o[dc] = __builtin_amdgcn_mfma_f32_16x16x32_bf16(vf, pf, o[dc], 0, 0, 0);
      }
    }

    cur ^= 1;
  }

  float inv = 1.f / ell;
#pragma unroll
  for (int dc = 0; dc < 4; ++dc) {
    bf16x4 ok4 = {(bf16)(o[dc][0] * inv), (bf16)(o[dc][1] * inv),
                  (bf16)(o[dc][2] * inv), (bf16)(o[dc][3] * inv)};
    *(bf16x4*)swz(&Plds[w][0], c, dc * 32 + g * 8) = ok4;
  }
  asm volatile("s_waitcnt lgkmcnt(0)" ::: "memory");
  __builtin_amdgcn_sched_barrier(0);
#pragma unroll
  for (int p = 0; p < 2; ++p) {
    int row = p * 8 + (l >> 3);
    bf16x8 vrow = *(const bf16x8*)swz(&Plds[w][0], row, (l & 7) * 16);
    *(bf16x8*)&att[(size_t)(b * 2048 + qt * 64 + w * 16 + row) * 1024 +
                   h * 64 + (l & 7) * 8] = vrow;
  }
}

// ---------------- launcher ----------------
extern "C" void kernel_launch(void* const* d_in, const int* in_sizes, int n_in,
                              void* d_out, int out_size, void* d_ws, size_t ws_size,
                              hipStream_t stream) {
  const float* x  = (const float*)d_in[0];
  const float* Wq = (const float*)d_in[1];
  const float* bq = (const float*)d_in[2];
  const float* Wk = (const float*)d_in[3];
  const float* bk = (const float*)d_in[4];
  const float* Wv = (const float*)d_in[5];
  const float* bv = (const float*)d_in[6];
  const float* Wp = (const float*)d_in[7];
  const float* bp = (const float*)d_in[8];
  float* out = (float*)d_out;

  char* ws = (char*)d_ws;
  const size_t MB = 1024 * 1024;
  bf16*  xb    = (bf16*)(ws);             // 8 MB [4096][1024]; reused as att
  bf16*  wqkvT = (bf16*)(ws + 8 * MB);    // 6 MB [3072][1024]
  bf16*  wpT   = (bf16*)(ws + 14 * MB);   // 2 MB [1024][1024]
  float* bcat  = (float*)(ws + 16 * MB);  // 12 KB
  bf16*  qkv   = (bf16*)(ws + 17 * MB);   // 24 MB [4096][3072]
  bf16*  vcb   = (bf16*)(ws + 41 * MB);   // 5.5 MB [32][64][1408]
  bf16*  att   = xb;                      // alias: xb dead after QKV GEMM

  // 1: all preps (cvt + 4x W^T + bias concat)
  k_prep<<<4108, 256, 0, stream>>>(x, Wq, Wk, Wv, Wp, bq, bk, bv,
                                   xb, wqkvT, wpT, bcat);
  // 2: QKV GEMM [4096,1024]x[1024,3072]
  k_gemm_bt<bf16><<<dim3(32, 24), 256, 0, stream>>>(xb, wqkvT, bcat, qkv, 1024, 3072);
  // 3: V gather/transpose only (K read directly from qkv by attn)
  k_compact<<<704, 256, 0, stream>>>(qkv, vcb);
  // 4: attention (R12 geometry, K direct)
  k_attn<<<1024, 256, 0, stream>>>(qkv, vcb, att);
  // 5: output projection
  k_gemm_bt<float><<<dim3(32, 8), 256, 0, stream>>>(att, wpT, bp, out, 1024, 1024);
}

// Round 15
// 105.371 us; speedup vs baseline: 1.0974x; 1.0065x over previous
//
#include <hip/hip_runtime.h>

#define AS_GLOBAL __attribute__((address_space(1)))
#define AS_LDS    __attribute__((address_space(3)))

typedef __bf16 bf16;
typedef __bf16 bf16x4 __attribute__((ext_vector_type(4)));
typedef __bf16 bf16x8 __attribute__((ext_vector_type(8)));
typedef float  f32x4  __attribute__((ext_vector_type(4)));
typedef unsigned short u16x8 __attribute__((ext_vector_type(8)));

__device__ __forceinline__ void gload16(const void* g, void* l) {
  __builtin_amdgcn_global_load_lds((const AS_GLOBAL unsigned int*)g,
                                   (AS_LDS unsigned int*)l, 16, 0, 0);
}

// swizzled LDS address for a [R][128B] row-major tile:
// stored_byte = row*128 + (bytecol ^ ((row&7)<<4))
__device__ __forceinline__ void* swz(void* base, int row, int bytecol) {
  return (char*)base + row * 128 + (bytecol ^ ((row & 7) << 4));
}

// compacted-column helpers: kept columns are s with !(s%3==1 && s>=4).
__device__ __forceinline__ int keptcnt(int X) { return X - ((X - 2) < 0 ? 0 : (X - 2) / 3); }
__device__ __forceinline__ int ci2s(int ci) {
  return 3 * ((ci - 2) >> 1) + 2 + ((ci - 2) & 1);
}
__device__ __forceinline__ int ci2s_full(int ci) {
  return ci < 2 ? ci : ci2s(ci);
}

// ---------------- fused prep: x->bf16 | 4x W^T | bias concat --------------
__global__ __launch_bounds__(256) void k_prep(const float* __restrict__ x,
                                              const float* __restrict__ Wq,
                                              const float* __restrict__ Wk,
                                              const float* __restrict__ Wv,
                                              const float* __restrict__ Wp,
                                              const float* __restrict__ bq,
                                              const float* __restrict__ bk,
                                              const float* __restrict__ bv,
                                              bf16* __restrict__ xb,
                                              bf16* __restrict__ wqkvT,
                                              bf16* __restrict__ wpT,
                                              float* __restrict__ bc) {
  int blk = blockIdx.x;
  if (blk < 2048) {
    int i = blk * 256 + threadIdx.x;
    const float4* p = (const float4*)(x + (size_t)i * 8);
    float4 a = p[0], b = p[1];
    bf16x8 v;
    v[0] = (bf16)a.x; v[1] = (bf16)a.y; v[2] = (bf16)a.z; v[3] = (bf16)a.w;
    v[4] = (bf16)b.x; v[5] = (bf16)b.y; v[6] = (bf16)b.z; v[7] = (bf16)b.w;
    *(bf16x8*)(xb + (size_t)i * 8) = v;
  } else if (blk < 4096) {
    int wblk = blk - 2048;
    int sel = wblk >> 9;
    const float* W = (sel == 0) ? Wq : (sel == 1) ? Wk : (sel == 2) ? Wv : Wp;
    bf16* dst = (sel < 3) ? (wqkvT + (size_t)sel * 1024 * 1024) : wpT;
    int lin = (wblk & 511) * 256 + threadIdx.x;
    int n = lin & 1023, kc = lin >> 10;
    bf16x8 v;
#pragma unroll
    for (int j = 0; j < 8; ++j) v[j] = (bf16)W[(size_t)(kc * 8 + j) * 1024 + n];
    *(bf16x8*)&dst[(size_t)n * 1024 + kc * 8] = v;
  } else {
    int i = (blk - 4096) * 256 + threadIdx.x;   // 0..3071
    bc[i] = (i < 1024) ? bq[i] : (i < 2048 ? bk[i - 1024] : bv[i - 2048]);
  }
}

// ---------------- V compact: gather + transpose -> Vc[bh][64][1408] -------
__global__ __launch_bounds__(256) void k_compact(const bf16* __restrict__ qkv,
                                                 bf16* __restrict__ vc) {
  __shared__ unsigned L[32 * 65];
  int blk = blockIdx.x;                 // 32 bh * 22 cichunks = 704
  int tid = threadIdx.x;
  int bh = blk / 22, cc = blk % 22;
  int b = bh >> 4, h = bh & 15;
  int ci0 = cc * 64;
  int p = tid >> 3, d0 = (tid & 7) * 8;
  int s0 = ci2s_full(ci0 + 2 * p), s1 = ci2s_full(ci0 + 2 * p + 1);
  u16x8 e = {}, od = {};
  if (s0 < 2048)
    e = *(const u16x8*)&qkv[(size_t)(b * 2048 + s0) * 3072 + 2048 + h * 64 + d0];
  if (s1 < 2048)
    od = *(const u16x8*)&qkv[(size_t)(b * 2048 + s1) * 3072 + 2048 + h * 64 + d0];
#pragma unroll
  for (int k2 = 0; k2 < 8; ++k2)
    L[p * 65 + d0 + k2] = (unsigned)e[k2] | ((unsigned)od[k2] << 16);
  __syncthreads();
#pragma unroll
  for (int it = 0; it < 2; ++it) {
    int d = it * 32 + (tid >> 3), jg = tid & 7;
    unsigned q4[4];
#pragma unroll
    for (int jj = 0; jj < 4; ++jj) q4[jj] = L[(jg * 4 + jj) * 65 + d];
    *(uint4*)&vc[((size_t)bh * 64 + d) * 1408 + ci0 + jg * 8] = *(uint4*)q4;
  }
}

// ---------------- 128^2 dbuf GEMM, templated BK -------------------------
// BK=32 (QKV: 3 blocks/CU, throughput-bound) | BK=64 (out-proj: 1 block/CU,
// chain-bound -> halved barrier count). Granule XOR-swizzle both sides.
template <typename OutT, int BK>
__global__ __launch_bounds__(256) void k_gemm_bt(const bf16* __restrict__ A,
                                                 const bf16* __restrict__ Bt,
                                                 const float* __restrict__ bias,
                                                 OutT* __restrict__ C,
                                                 int K, int N) {
  constexpr int GR = BK / 8;            // 16B granules per LDS row
  __shared__ bf16 As[2][128 * BK];
  __shared__ bf16 Bs[2][128 * BK];
  const int tid = threadIdx.x;
  const int w = tid >> 6, l = tid & 63, g = l >> 4, c = l & 15;
  const int wr = w >> 1, wc = w & 1;
  int lin = blockIdx.y * gridDim.x + blockIdx.x;
  int chunk = (gridDim.x * gridDim.y) >> 3;
  int nl = (lin & 7) * chunk + (lin >> 3);
  const int row0 = (nl % gridDim.x) * 128, col0 = (nl / gridDim.x) * 128;
  f32x4 acc[4][4] = {};

  auto stage = [&](int buf, int k0) {
#pragma unroll
    for (int it = 0; it < (128 * GR) / 256; ++it) {
      int idx = it * 256 + tid;
      int r = idx / GR, j = idx % GR;
      int jj;
      if constexpr (BK == 32) jj = j ^ ((r >> 1) & 3);
      else                    jj = j ^ (r & 7);
      gload16(A  + (size_t)(row0 + r) * K + k0 + jj * 8, &As[buf][idx * 8]);
      gload16(Bt + (size_t)(col0 + r) * K + k0 + jj * 8, &Bs[buf][idx * 8]);
    }
  };

  stage(0, 0);
  int cur = 0;
#pragma unroll 1
  for (int k0 = 0; k0 < K; k0 += BK) {
    __syncthreads();   // drains vmcnt (stage(k0) landed) + full memory fence

    if (k0 + BK < K) stage(cur ^ 1, k0 + BK);

    bf16x8 af[4][BK / 32], bfr[4][BK / 32];
#pragma unroll
    for (int m = 0; m < 4; ++m) {
      int row = wr * 64 + m * 16 + c;
#pragma unroll
      for (int kk = 0; kk < BK / 32; ++kk) {
        int gg;
        if constexpr (BK == 32) gg = g ^ ((row >> 1) & 3);
        else                    gg = (kk * 4 + g) ^ (row & 7);
        af[m][kk] = *(const bf16x8*)&As[cur][row * BK + gg * 8];
      }
    }
#pragma unroll
    for (int n = 0; n < 4; ++n) {
      int row = wc * 64 + n * 16 + c;
#pragma unroll
      for (int kk = 0; kk < BK / 32; ++kk) {
        int gg;
        if constexpr (BK == 32) gg = g ^ ((row >> 1) & 3);
        else                    gg = (kk * 4 + g) ^ (row & 7);
        bfr[n][kk] = *(const bf16x8*)&Bs[cur][row * BK + gg * 8];
      }
    }
#pragma unroll
    for (int m = 0; m < 4; ++m)
#pragma unroll
      for (int n = 0; n < 4; ++n)
#pragma unroll
        for (int kk = 0; kk < BK / 32; ++kk)
          acc[m][n] = __builtin_amdgcn_mfma_f32_16x16x32_bf16(af[m][kk], bfr[n][kk],
                                                              acc[m][n], 0, 0, 0);
    cur ^= 1;
  }

#pragma unroll
  for (int m = 0; m < 4; ++m) {
    int row = row0 + wr * 64 + m * 16 + g * 4;
#pragma unroll
    for (int n = 0; n < 4; ++n) {
      int col = col0 + wc * 64 + n * 16 + c;
      float bv = bias[col];
#pragma unroll
      for (int r = 0; r < 4; ++r) {
        float v = acc[m][n][r] + bv;
        C[(size_t)(row + r) * N + col] = (OutT)v;
      }
    }
  }
}

// ---------------- flash attention v11: exp2-domain + defer-max ------------
// R12 geometry (1024 blocks, 64 q-rows, 4 waves, 40KB, 4 blocks/CU).
// Q pre-scaled by 0.125*log2(e) -> S in log2 domain, P = exp2(S - m)
// (exp2f = bare v_exp_f32, saves 16 v_mul/tile). Defer-max (T13, THR=12):
// skip o-rescale + m-update when no lane's max grew >12 (P bounded 2^12,
// bf16-safe). ell kept per-lane partial; single cross-lane reduce at end.
__global__ __launch_bounds__(256, 4) void k_attn(const bf16* __restrict__ qkv,
                                                 const bf16* __restrict__ vc,
                                                 bf16* __restrict__ att) {
  const int idx = blockIdx.x;
  const int slot = idx >> 8, j = idx & 255;
  const int r8 = j >> 5, bh = j & 31;
  const int b = bh >> 4, h = bh & 15;
  int qt;
  switch (slot) {
    case 0: qt = r8;       break;
    case 1: qt = 31 - r8;  break;
    case 2: qt = r8 + 8;   break;
    default: qt = 23 - r8; break;
  }

  const int tid = threadIdx.x;
  const int w = tid >> 6, l = tid & 63, g = l >> 4, c = l & 15;
  const int qw0 = qt * 64 + w * 16;
  const int qq = qw0 + c;

  const int nt = (keptcnt(qt * 64 + 64) + 63) >> 6;
  const int tmaskw = keptcnt(qw0 + 1) >> 6;

  __shared__ bf16 Ks[2][64 * 64];
  __shared__ bf16 Vs[2][64 * 64];
  __shared__ bf16 Plds[4][16 * 64];

  const bf16* vgc = vc + (size_t)bh * 64 * 1408;

  auto stage = [&](int buf, int t) {
    int s0 = t * 64;
#pragma unroll
    for (int it = 0; it < 2; ++it) {
      int ch = it * 256 + tid;
      int rr = ch >> 3, jj = (ch & 7) ^ (rr & 7);
      int s = ci2s_full(s0 + rr);
      s = (s < 2048) ? s : 0;             // pad: load row 0; masked by s<=qq
      gload16(qkv + (size_t)(b * 2048 + s) * 3072 + 1024 + h * 64 + jj * 8,
              &Ks[buf][ch * 8]);
      gload16(vgc + (size_t)rr * 1408 + s0 + jj * 8, &Vs[buf][ch * 8]);
    }
  };

  // Q B-frag, pre-scaled by 0.125*log2e -> S in log2 domain
  const float QSCL = 0.125f * 1.44269504f;
  const bf16* qb = qkv + (size_t)(b * 2048 + qq) * 3072 + h * 64 + g * 8;
  bf16x8 qf0 = *(const bf16x8*)qb;
  bf16x8 qf1 = *(const bf16x8*)(qb + 32);
#pragma unroll
  for (int jq = 0; jq < 8; ++jq) {
    qf0[jq] = (bf16)((float)qf0[jq] * QSCL);
    qf1[jq] = (bf16)((float)qf1[jq] * QSCL);
  }

  f32x4 o[4] = {};
  float mrow = -1e30f, ell = 0.f;   // ell = per-lane partial (16 s-cols)

  stage(0, 0);

  int cur = 0;
#pragma unroll 1
  for (int t = 0; t < nt; ++t) {
    __syncthreads();   // stage(t) landed everywhere; all waves done with t-1

    if (t + 1 < nt) stage(cur ^ 1, t + 1);

    f32x4 ss[4] = {};
#pragma unroll
    for (int st = 0; st < 4; ++st) {
      bf16x8 ka  = *(const bf16x8*)swz(&Ks[cur][0], st * 16 + c, g * 16);
      bf16x8 kb2 = *(const bf16x8*)swz(&Ks[cur][0], st * 16 + c, 64 + g * 16);
      ss[st] = __builtin_amdgcn_mfma_f32_16x16x32_bf16(ka,  qf0, ss[st], 0, 0, 0);
      ss[st] = __builtin_amdgcn_mfma_f32_16x16x32_bf16(kb2, qf1, ss[st], 0, 0, 0);
    }

    float mloc = -1e30f;
    if (t >= tmaskw) {
#pragma unroll
      for (int st = 0; st < 4; ++st)
#pragma unroll
        for (int r = 0; r < 4; ++r) {
          int ci = t * 64 + st * 16 + g * 4 + r;
          int s = ci2s(ci);
          if (t == 0) s = (ci < 2) ? ci : s;
          float v = (s <= qq) ? ss[st][r] : -1e30f;
          ss[st][r] = v;
          mloc = fmaxf(mloc, v);
        }
    } else {
#pragma unroll
      for (int st = 0; st < 4; ++st)
#pragma unroll
        for (int r = 0; r < 4; ++r) mloc = fmaxf(mloc, ss[st][r]);
    }
    mloc = fmaxf(mloc, __shfl_xor(mloc, 16));
    mloc = fmaxf(mloc, __shfl_xor(mloc, 32));

    // defer-max: rescale only when some row's max grew by >12 (log2 units)
    if (!__all(mloc - mrow <= 12.0f)) {
      float mn = fmaxf(mrow, mloc);
      float al = exp2f(mrow - mn);
      mrow = mn;
      ell *= al;
#pragma unroll
      for (int dc = 0; dc < 4; ++dc)
#pragma unroll
        for (int r = 0; r < 4; ++r) o[dc][r] *= al;
    }

    float rsum = 0.f;
#pragma unroll
    for (int st = 0; st < 4; ++st) {
      float p0 = exp2f(ss[st][0] - mrow);
      float p1 = exp2f(ss[st][1] - mrow);
      float p2 = exp2f(ss[st][2] - mrow);
      float p3 = exp2f(ss[st][3] - mrow);
      rsum += (p0 + p1) + (p2 + p3);
      bf16x4 pk = {(bf16)p0, (bf16)p1, (bf16)p2, (bf16)p3};
      *(bf16x4*)swz(&Plds[w][0], c, st * 32 + g * 8) = pk;
    }
    ell += rsum;       // per-lane partial; cross-lane reduced once at end

    // wave-private P cross-lane round trip (rule #18 fence pair)
    asm volatile("s_waitcnt lgkmcnt(0)" ::: "memory");
    __builtin_amdgcn_sched_barrier(0);

#pragma unroll
    for (int kk = 0; kk < 2; ++kk) {
      bf16x8 pf = *(const bf16x8*)swz(&Plds[w][0], c, kk * 64 + g * 16);
#pragma unroll
      for (int dc = 0; dc < 4; ++dc) {
        bf16x8 vf = *(const bf16x8*)swz(&Vs[cur][0], dc * 16 + c, kk * 64 + g * 16);
        o[dc] = __builtin_amdgcn_mfma_f32_16x16x32_bf16(vf, pf, o[dc], 0, 0, 0);
      }
    }

    cur ^= 1;
  }

  // ---- epilogue: reduce ell across the 4 g-lanes (same q=c row) ----
  float et = ell;
  et += __shfl_xor(et, 16);
  et += __shfl_xor(et, 32);
  float inv = 1.f / et;
#pragma unroll
  for (int dc = 0; dc < 4; ++dc) {
    bf16x4 ok4 = {(bf16)(o[dc][0] * inv), (bf16)(o[dc][1] * inv),
                  (bf16)(o[dc][2] * inv), (bf16)(o[dc][3] * inv)};
    *(bf16x4*)swz(&Plds[w][0], c, dc * 32 + g * 8) = ok4;
  }
  asm volatile("s_waitcnt lgkmcnt(0)" ::: "memory");
  __builtin_amdgcn_sched_barrier(0);
#pragma unroll
  for (int p = 0; p < 2; ++p) {
    int row = p * 8 + (l >> 3);
    bf16x8 vrow = *(const bf16x8*)swz(&Plds[w][0], row, (l & 7) * 16);
    *(bf16x8*)&att[(size_t)(b * 2048 + qt * 64 + w * 16 + row) * 1024 +
                   h * 64 + (l & 7) * 8] = vrow;
  }
}

// ---------------- launcher ----------------
extern "C" void kernel_launch(void* const* d_in, const int* in_sizes, int n_in,
                              void* d_out, int out_size, void* d_ws, size_t ws_size,
                              hipStream_t stream) {
  const float* x  = (const float*)d_in[0];
  const float* Wq = (const float*)d_in[1];
  const float* bq = (const float*)d_in[2];
  const float* Wk = (const float*)d_in[3];
  const float* bk = (const float*)d_in[4];
  const float* Wv = (const float*)d_in[5];
  const float* bv = (const float*)d_in[6];
  const float* Wp = (const float*)d_in[7];
  const float* bp = (const float*)d_in[8];
  float* out = (float*)d_out;

  char* ws = (char*)d_ws;
  const size_t MB = 1024 * 1024;
  bf16*  xb    = (bf16*)(ws);             // 8 MB [4096][1024]; reused as att
  bf16*  wqkvT = (bf16*)(ws + 8 * MB);    // 6 MB [3072][1024]
  bf16*  wpT   = (bf16*)(ws + 14 * MB);   // 2 MB [1024][1024]
  float* bcat  = (float*)(ws + 16 * MB);  // 12 KB
  bf16*  qkv   = (bf16*)(ws + 17 * MB);   // 24 MB [4096][3072]
  bf16*  vcb   = (bf16*)(ws + 41 * MB);   // 5.5 MB [32][64][1408]
  bf16*  att   = xb;                      // alias: xb dead after QKV GEMM

  // 1: all preps (cvt + 4x W^T + bias concat)
  k_prep<<<4108, 256, 0, stream>>>(x, Wq, Wk, Wv, Wp, bq, bk, bv,
                                   xb, wqkvT, wpT, bcat);
  // 2: QKV GEMM [4096,1024]x[1024,3072]
  k_gemm_bt<bf16, 32><<<dim3(32, 24), 256, 0, stream>>>(xb, wqkvT, bcat, qkv,
                                                        1024, 3072);
  // 3: V gather/transpose only (K read directly from qkv by attn)
  k_compact<<<704, 256, 0, stream>>>(qkv, vcb);
  // 4: attention (R12 geometry + exp2/defer-max/deferred-ell)
  k_attn<<<1024, 256, 0, stream>>>(qkv, vcb, att);
  // 5: output projection (BK=64: halved chain at unchanged 1 block/CU)
  k_gemm_bt<float, 64><<<dim3(32, 8), 256, 0, stream>>>(att, wpT, bp, out,
                                                        1024, 1024);
}

// Round 16
// 102.993 us; speedup vs baseline: 1.1228x; 1.0231x over previous
//
#include <hip/hip_runtime.h>

#define AS_GLOBAL __attribute__((address_space(1)))
#define AS_LDS    __attribute__((address_space(3)))

typedef __bf16 bf16;
typedef __bf16 bf16x4 __attribute__((ext_vector_type(4)));
typedef __bf16 bf16x8 __attribute__((ext_vector_type(8)));
typedef float  f32x4  __attribute__((ext_vector_type(4)));
typedef unsigned short u16x8 __attribute__((ext_vector_type(8)));

__device__ __forceinline__ void gload16(const void* g, void* l) {
  __builtin_amdgcn_global_load_lds((const AS_GLOBAL unsigned int*)g,
                                   (AS_LDS unsigned int*)l, 16, 0, 0);
}

// swizzled LDS address for a [R][128B] row-major tile:
// stored_byte = row*128 + (bytecol ^ ((row&7)<<4))
__device__ __forceinline__ void* swz(void* base, int row, int bytecol) {
  return (char*)base + row * 128 + (bytecol ^ ((row & 7) << 4));
}

// compacted-column helpers: kept columns are s with !(s%3==1 && s>=4).
__device__ __forceinline__ int keptcnt(int X) { return X - ((X - 2) < 0 ? 0 : (X - 2) / 3); }
__device__ __forceinline__ int ci2s(int ci) {
  return 3 * ((ci - 2) >> 1) + 2 + ((ci - 2) & 1);
}
__device__ __forceinline__ int ci2s_full(int ci) {
  return ci < 2 ? ci : ci2s(ci);
}

// ---------------- fused prep: x->bf16 | 4x W^T | bias concat --------------
__global__ __launch_bounds__(256) void k_prep(const float* __restrict__ x,
                                              const float* __restrict__ Wq,
                                              const float* __restrict__ Wk,
                                              const float* __restrict__ Wv,
                                              const float* __restrict__ Wp,
                                              const float* __restrict__ bq,
                                              const float* __restrict__ bk,
                                              const float* __restrict__ bv,
                                              bf16* __restrict__ xb,
                                              bf16* __restrict__ wqkvT,
                                              bf16* __restrict__ wpT,
                                              float* __restrict__ bc) {
  int blk = blockIdx.x;
  if (blk < 2048) {
    int i = blk * 256 + threadIdx.x;
    const float4* p = (const float4*)(x + (size_t)i * 8);
    float4 a = p[0], b = p[1];
    bf16x8 v;
    v[0] = (bf16)a.x; v[1] = (bf16)a.y; v[2] = (bf16)a.z; v[3] = (bf16)a.w;
    v[4] = (bf16)b.x; v[5] = (bf16)b.y; v[6] = (bf16)b.z; v[7] = (bf16)b.w;
    *(bf16x8*)(xb + (size_t)i * 8) = v;
  } else if (blk < 4096) {
    int wblk = blk - 2048;
    int sel = wblk >> 9;
    const float* W = (sel == 0) ? Wq : (sel == 1) ? Wk : (sel == 2) ? Wv : Wp;
    bf16* dst = (sel < 3) ? (wqkvT + (size_t)sel * 1024 * 1024) : wpT;
    int lin = (wblk & 511) * 256 + threadIdx.x;
    int n = lin & 1023, kc = lin >> 10;
    bf16x8 v;
#pragma unroll
    for (int j = 0; j < 8; ++j) v[j] = (bf16)W[(size_t)(kc * 8 + j) * 1024 + n];
    *(bf16x8*)&dst[(size_t)n * 1024 + kc * 8] = v;
  } else {
    int i = (blk - 4096) * 256 + threadIdx.x;   // 0..3071
    bc[i] = (i < 1024) ? bq[i] : (i < 2048 ? bk[i - 1024] : bv[i - 2048]);
  }
}

// ---------------- V compact: gather + transpose -> Vc[bh][64][1408] -------
__global__ __launch_bounds__(256) void k_compact(const bf16* __restrict__ qkv,
                                                 bf16* __restrict__ vc) {
  __shared__ unsigned L[32 * 65];
  int blk = blockIdx.x;                 // 32 bh * 22 cichunks = 704
  int tid = threadIdx.x;
  int bh = blk / 22, cc = blk % 22;
  int b = bh >> 4, h = bh & 15;
  int ci0 = cc * 64;
  int p = tid >> 3, d0 = (tid & 7) * 8;
  int s0 = ci2s_full(ci0 + 2 * p), s1 = ci2s_full(ci0 + 2 * p + 1);
  u16x8 e = {}, od = {};
  if (s0 < 2048)
    e = *(const u16x8*)&qkv[(size_t)(b * 2048 + s0) * 3072 + 2048 + h * 64 + d0];
  if (s1 < 2048)
    od = *(const u16x8*)&qkv[(size_t)(b * 2048 + s1) * 3072 + 2048 + h * 64 + d0];
#pragma unroll
  for (int k2 = 0; k2 < 8; ++k2)
    L[p * 65 + d0 + k2] = (unsigned)e[k2] | ((unsigned)od[k2] << 16);
  __syncthreads();
#pragma unroll
  for (int it = 0; it < 2; ++it) {
    int d = it * 32 + (tid >> 3), jg = tid & 7;
    unsigned q4[4];
#pragma unroll
    for (int jj = 0; jj < 4; ++jj) q4[jj] = L[(jg * 4 + jj) * 65 + d];
    *(uint4*)&vc[((size_t)bh * 64 + d) * 1408 + ci0 + jg * 8] = *(uint4*)q4;
  }
}

// ---------------- dbuf GEMM, templated tile TMxTN, BK ---------------------
// 4 waves as 2x2; wave tile (TM/2)x(TN/2). Granule XOR-swizzle both sides.
// QKV: <bf16,128,128,32> (768 blocks, 3/CU). Out-proj: <float,64,128,64>
// (512 blocks, 2/CU: doubles per-CU overlap at 1-block-exposed latency).
template <typename OutT, int TM, int TN, int BK>
__global__ __launch_bounds__(256) void k_gemm_bt(const bf16* __restrict__ A,
                                                 const bf16* __restrict__ Bt,
                                                 const float* __restrict__ bias,
                                                 OutT* __restrict__ C,
                                                 int K, int N) {
  constexpr int GR = BK / 8;            // 16B granules per LDS row
  constexpr int MF = TM / 32, NF = TN / 32, KF = BK / 32;
  __shared__ bf16 As[2][TM * BK];
  __shared__ bf16 Bs[2][TN * BK];
  const int tid = threadIdx.x;
  const int w = tid >> 6, l = tid & 63, g = l >> 4, c = l & 15;
  const int wr = w >> 1, wc = w & 1;
  int lin = blockIdx.y * gridDim.x + blockIdx.x;
  int chunk = (gridDim.x * gridDim.y) >> 3;
  int nl = (lin & 7) * chunk + (lin >> 3);
  const int row0 = (nl % gridDim.x) * TM, col0 = (nl / gridDim.x) * TN;
  f32x4 acc[MF][NF] = {};

  auto swzj = [&](int j, int r) {
    if constexpr (BK == 32) return j ^ ((r >> 1) & 3);
    else                    return j ^ (r & 7);
  };

  auto stage = [&](int buf, int k0) {
#pragma unroll
    for (int it = 0; it < (TM * GR) / 256; ++it) {
      int idx = it * 256 + tid;
      int r = idx / GR, j = idx % GR;
      gload16(A + (size_t)(row0 + r) * K + k0 + swzj(j, r) * 8, &As[buf][idx * 8]);
    }
#pragma unroll
    for (int it = 0; it < (TN * GR) / 256; ++it) {
      int idx = it * 256 + tid;
      int r = idx / GR, j = idx % GR;
      gload16(Bt + (size_t)(col0 + r) * K + k0 + swzj(j, r) * 8, &Bs[buf][idx * 8]);
    }
  };

  stage(0, 0);
  int cur = 0;
#pragma unroll 1
  for (int k0 = 0; k0 < K; k0 += BK) {
    __syncthreads();   // drains vmcnt (stage(k0) landed) + full memory fence

    if (k0 + BK < K) stage(cur ^ 1, k0 + BK);

    bf16x8 af[MF][KF], bfr[NF][KF];
#pragma unroll
    for (int m = 0; m < MF; ++m) {
      int row = wr * (TM / 2) + m * 16 + c;
#pragma unroll
      for (int kk = 0; kk < KF; ++kk)
        af[m][kk] = *(const bf16x8*)&As[cur][row * BK + swzj(kk * 4 + g, row) * 8];
    }
#pragma unroll
    for (int n = 0; n < NF; ++n) {
      int row = wc * (TN / 2) + n * 16 + c;
#pragma unroll
      for (int kk = 0; kk < KF; ++kk)
        bfr[n][kk] = *(const bf16x8*)&Bs[cur][row * BK + swzj(kk * 4 + g, row) * 8];
    }
#pragma unroll
    for (int m = 0; m < MF; ++m)
#pragma unroll
      for (int n = 0; n < NF; ++n)
#pragma unroll
        for (int kk = 0; kk < KF; ++kk)
          acc[m][n] = __builtin_amdgcn_mfma_f32_16x16x32_bf16(af[m][kk], bfr[n][kk],
                                                              acc[m][n], 0, 0, 0);
    cur ^= 1;
  }

#pragma unroll
  for (int m = 0; m < MF; ++m) {
    int row = row0 + wr * (TM / 2) + m * 16 + g * 4;
#pragma unroll
    for (int n = 0; n < NF; ++n) {
      int col = col0 + wc * (TN / 2) + n * 16 + c;
      float bv = bias[col];
#pragma unroll
      for (int r = 0; r < 4; ++r) {
        float v = acc[m][n][r] + bv;
        C[(size_t)(row + r) * N + col] = (OutT)v;
      }
    }
  }
}

// ---------------- flash attention v12: v11 + T5 setprio -------------------
// R12 geometry (1024 blocks, 64 q-rows, 4 waves, 40KB, 4 blocks/CU).
// 4 independent blocks/CU = inter-block phase diversity -> setprio(1)
// around MFMA clusters keeps the matrix pipe fed (T5, m191 mechanism).
__global__ __launch_bounds__(256, 4) void k_attn(const bf16* __restrict__ qkv,
                                                 const bf16* __restrict__ vc,
                                                 bf16* __restrict__ att) {
  const int idx = blockIdx.x;
  const int slot = idx >> 8, j = idx & 255;
  const int r8 = j >> 5, bh = j & 31;
  const int b = bh >> 4, h = bh & 15;
  int qt;
  switch (slot) {
    case 0: qt = r8;       break;
    case 1: qt = 31 - r8;  break;
    case 2: qt = r8 + 8;   break;
    default: qt = 23 - r8; break;
  }

  const int tid = threadIdx.x;
  const int w = tid >> 6, l = tid & 63, g = l >> 4, c = l & 15;
  const int qw0 = qt * 64 + w * 16;
  const int qq = qw0 + c;

  const int nt = (keptcnt(qt * 64 + 64) + 63) >> 6;
  const int tmaskw = keptcnt(qw0 + 1) >> 6;

  __shared__ bf16 Ks[2][64 * 64];
  __shared__ bf16 Vs[2][64 * 64];
  __shared__ bf16 Plds[4][16 * 64];

  const bf16* vgc = vc + (size_t)bh * 64 * 1408;

  auto stage = [&](int buf, int t) {
    int s0 = t * 64;
#pragma unroll
    for (int it = 0; it < 2; ++it) {
      int ch = it * 256 + tid;
      int rr = ch >> 3, jj = (ch & 7) ^ (rr & 7);
      int s = ci2s_full(s0 + rr);
      s = (s < 2048) ? s : 0;             // pad: load row 0; masked by s<=qq
      gload16(qkv + (size_t)(b * 2048 + s) * 3072 + 1024 + h * 64 + jj * 8,
              &Ks[buf][ch * 8]);
      gload16(vgc + (size_t)rr * 1408 + s0 + jj * 8, &Vs[buf][ch * 8]);
    }
  };

  // Q B-frag, pre-scaled by 0.125*log2e -> S in log2 domain
  const float QSCL = 0.125f * 1.44269504f;
  const bf16* qb = qkv + (size_t)(b * 2048 + qq) * 3072 + h * 64 + g * 8;
  bf16x8 qf0 = *(const bf16x8*)qb;
  bf16x8 qf1 = *(const bf16x8*)(qb + 32);
#pragma unroll
  for (int jq = 0; jq < 8; ++jq) {
    qf0[jq] = (bf16)((float)qf0[jq] * QSCL);
    qf1[jq] = (bf16)((float)qf1[jq] * QSCL);
  }

  f32x4 o[4] = {};
  float mrow = -1e30f, ell = 0.f;   // ell = per-lane partial (16 s-cols)

  stage(0, 0);

  int cur = 0;
#pragma unroll 1
  for (int t = 0; t < nt; ++t) {
    __syncthreads();   // stage(t) landed everywhere; all waves done with t-1

    if (t + 1 < nt) stage(cur ^ 1, t + 1);

    f32x4 ss[4] = {};
    __builtin_amdgcn_s_setprio(1);
#pragma unroll
    for (int st = 0; st < 4; ++st) {
      bf16x8 ka  = *(const bf16x8*)swz(&Ks[cur][0], st * 16 + c, g * 16);
      bf16x8 kb2 = *(const bf16x8*)swz(&Ks[cur][0], st * 16 + c, 64 + g * 16);
      ss[st] = __builtin_amdgcn_mfma_f32_16x16x32_bf16(ka,  qf0, ss[st], 0, 0, 0);
      ss[st] = __builtin_amdgcn_mfma_f32_16x16x32_bf16(kb2, qf1, ss[st], 0, 0, 0);
    }
    __builtin_amdgcn_s_setprio(0);

    float mloc = -1e30f;
    if (t >= tmaskw) {
#pragma unroll
      for (int st = 0; st < 4; ++st)
#pragma unroll
        for (int r = 0; r < 4; ++r) {
          int ci = t * 64 + st * 16 + g * 4 + r;
          int s = ci2s(ci);
          if (t == 0) s = (ci < 2) ? ci : s;
          float v = (s <= qq) ? ss[st][r] : -1e30f;
          ss[st][r] = v;
          mloc = fmaxf(mloc, v);
        }
    } else {
#pragma unroll
      for (int st = 0; st < 4; ++st)
#pragma unroll
        for (int r = 0; r < 4; ++r) mloc = fmaxf(mloc, ss[st][r]);
    }
    mloc = fmaxf(mloc, __shfl_xor(mloc, 16));
    mloc = fmaxf(mloc, __shfl_xor(mloc, 32));

    // defer-max: rescale only when some row's max grew by >12 (log2 units)
    if (!__all(mloc - mrow <= 12.0f)) {
      float mn = fmaxf(mrow, mloc);
      float al = exp2f(mrow - mn);
      mrow = mn;
      ell *= al;
#pragma unroll
      for (int dc = 0; dc < 4; ++dc)
#pragma unroll
        for (int r = 0; r < 4; ++r) o[dc][r] *= al;
    }

    float rsum = 0.f;
#pragma unroll
    for (int st = 0; st < 4; ++st) {
      float p0 = exp2f(ss[st][0] - mrow);
      float p1 = exp2f(ss[st][1] - mrow);
      float p2 = exp2f(ss[st][2] - mrow);
      float p3 = exp2f(ss[st][3] - mrow);
      rsum += (p0 + p1) + (p2 + p3);
      bf16x4 pk = {(bf16)p0, (bf16)p1, (bf16)p2, (bf16)p3};
      *(bf16x4*)swz(&Plds[w][0], c, st * 32 + g * 8) = pk;
    }
    ell += rsum;       // per-lane partial; cross-lane reduced once at end

    // wave-private P cross-lane round trip (rule #18 fence pair)
    asm volatile("s_waitcnt lgkmcnt(0)" ::: "memory");
    __builtin_amdgcn_sched_barrier(0);

    __builtin_amdgcn_s_setprio(1);
#pragma unroll
    for (int kk = 0; kk < 2; ++kk) {
      bf16x8 pf = *(const bf16x8*)swz(&Plds[w][0], c, kk * 64 + g * 16);
#pragma unroll
      for (int dc = 0; dc < 4; ++dc) {
        bf16x8 vf = *(const bf16x8*)swz(&Vs[cur][0], dc * 16 + c, kk * 64 + g * 16);
        o[dc] = __builtin_amdgcn_mfma_f32_16x16x32_bf16(vf, pf, o[dc], 0, 0, 0);
      }
    }
    __builtin_amdgcn_s_setprio(0);

    cur ^= 1;
  }

  // ---- epilogue: reduce ell across the 4 g-lanes (same q=c row) ----
  float et = ell;
  et += __shfl_xor(et, 16);
  et += __shfl_xor(et, 32);
  float inv = 1.f / et;
#pragma unroll
  for (int dc = 0; dc < 4; ++dc) {
    bf16x4 ok4 = {(bf16)(o[dc][0] * inv), (bf16)(o[dc][1] * inv),
                  (bf16)(o[dc][2] * inv), (bf16)(o[dc][3] * inv)};
    *(bf16x4*)swz(&Plds[w][0], c, dc * 32 + g * 8) = ok4;
  }
  asm volatile("s_waitcnt lgkmcnt(0)" ::: "memory");
  __builtin_amdgcn_sched_barrier(0);
#pragma unroll
  for (int p = 0; p < 2; ++p) {
    int row = p * 8 + (l >> 3);
    bf16x8 vrow = *(const bf16x8*)swz(&Plds[w][0], row, (l & 7) * 16);
    *(bf16x8*)&att[(size_t)(b * 2048 + qt * 64 + w * 16 + row) * 1024 +
                   h * 64 + (l & 7) * 8] = vrow;
  }
}

// ---------------- launcher ----------------
extern "C" void kernel_launch(void* const* d_in, const int* in_sizes, int n_in,
                              void* d_out, int out_size, void* d_ws, size_t ws_size,
                              hipStream_t stream) {
  const float* x  = (const float*)d_in[0];
  const float* Wq = (const float*)d_in[1];
  const float* bq = (const float*)d_in[2];
  const float* Wk = (const float*)d_in[3];
  const float* bk = (const float*)d_in[4];
  const float* Wv = (const float*)d_in[5];
  const float* bv = (const float*)d_in[6];
  const float* Wp = (const float*)d_in[7];
  const float* bp = (const float*)d_in[8];
  float* out = (float*)d_out;

  char* ws = (char*)d_ws;
  const size_t MB = 1024 * 1024;
  bf16*  xb    = (bf16*)(ws);             // 8 MB [4096][1024]; reused as att
  bf16*  wqkvT = (bf16*)(ws + 8 * MB);    // 6 MB [3072][1024]
  bf16*  wpT   = (bf16*)(ws + 14 * MB);   // 2 MB [1024][1024]
  float* bcat  = (float*)(ws + 16 * MB);  // 12 KB
  bf16*  qkv   = (bf16*)(ws + 17 * MB);   // 24 MB [4096][3072]
  bf16*  vcb   = (bf16*)(ws + 41 * MB);   // 5.5 MB [32][64][1408]
  bf16*  att   = xb;                      // alias: xb dead after QKV GEMM

  // 1: all preps (cvt + 4x W^T + bias concat)
  k_prep<<<4108, 256, 0, stream>>>(x, Wq, Wk, Wv, Wp, bq, bk, bv,
                                   xb, wqkvT, wpT, bcat);
  // 2: QKV GEMM [4096,1024]x[1024,3072], 128x128 tiles (768 blocks, 3/CU)
  k_gemm_bt<bf16, 128, 128, 32><<<dim3(32, 24), 256, 0, stream>>>(
      xb, wqkvT, bcat, qkv, 1024, 3072);
  // 3: V gather/transpose only (K read directly from qkv by attn)
  k_compact<<<704, 256, 0, stream>>>(qkv, vcb);
  // 4: attention (R12 geometry + setprio)
  k_attn<<<1024, 256, 0, stream>>>(qkv, vcb, att);
  // 5: output projection, 64x128 tiles (512 blocks = 2/CU overlap), BK=64
  k_gemm_bt<float, 64, 128, 64><<<dim3(64, 8), 256, 0, stream>>>(
      att, wpT, bp, out, 1024, 1024);
}